// Round 1
// baseline (1345.639 us; speedup 1.0000x reference)
//
#include <hip/hip_runtime.h>

#define DEV __device__ __forceinline__

typedef __attribute__((ext_vector_type(4))) float f4;
typedef __attribute__((ext_vector_type(8))) __bf16 bfrag;
typedef __attribute__((ext_vector_type(4))) unsigned short us4;
typedef __attribute__((ext_vector_type(8))) unsigned short us8;

// problem constants
#define NTOK   4096
#define DMODEL 2048
#define NEXP   64
#define MAXLD  304
#define NSLOT  19456   // 64*304

DEV unsigned short f2bf(float f){
  union { float f; unsigned int i; } u; u.f = f;
  unsigned int r = u.i + 0x7fffu + ((u.i >> 16) & 1u);
  return (unsigned short)(r >> 16);
}
DEV float bf2f(unsigned short b){
  union { unsigned int i; float f; } u; u.i = ((unsigned int)b) << 16;
  return u.f;
}

DEV void gl_lds16(const unsigned short* g, unsigned short* l){
  __builtin_amdgcn_global_load_lds(
      (const __attribute__((address_space(1))) void*)g,
      (__attribute__((address_space(3))) void*)l, 16, 0, 0);
}

// ---------------- generic C = A @ B^T GEMM ----------------
// A: M x K bf16 (row-major, lda=K), B: N x K bf16 (row-major, ldb=K).
// 128x128 tile, BK=32, 4 waves, each wave 64x64 via 4x4 16x16x32 MFMA frags.
// grid.z = group index with element strides sA/sB/sC (0 for plain GEMM).
// EPI: 0 = bf16 out, 1 = f32 out, 2 = f32 out = (acc + addin)*0.5
template<int EPI>
__global__ __launch_bounds__(256) void gemm_bt(
    const unsigned short* __restrict__ A, const unsigned short* __restrict__ B,
    void* __restrict__ Cp, const float* __restrict__ addin,
    int M, int N, int K, long long sA, long long sB, long long sC)
{
  __shared__ unsigned short As[128*32];
  __shared__ unsigned short Bs[128*32];
  A += (long long)blockIdx.z * sA;
  B += (long long)blockIdx.z * sB;
  const long long cbase = (long long)blockIdx.z * sC;
  const int bm = blockIdx.y * 128, bn = blockIdx.x * 128;
  const int t = threadIdx.x, wave = t >> 6, lane = t & 63;
  const int wm = (wave >> 1) * 64, wn = (wave & 1) * 64;
  const int fr = lane & 15, kg = lane >> 4;

  f4 acc[4][4];
#pragma unroll
  for (int m = 0; m < 4; ++m)
#pragma unroll
    for (int n = 0; n < 4; ++n)
      acc[m][n] = f4{0.f, 0.f, 0.f, 0.f};

  // staging: idx (0..511) covers the 128x32 tile, 16B per idx, row = idx>>2
  const int i0 = t, i1 = 256 + t;
  int ar0 = bm + (i0 >> 2); if (ar0 > M - 1) ar0 = M - 1;
  int ar1 = bm + (i1 >> 2); if (ar1 > M - 1) ar1 = M - 1;
  int br0 = bn + (i0 >> 2); if (br0 > N - 1) br0 = N - 1;
  int br1 = bn + (i1 >> 2); if (br1 > N - 1) br1 = N - 1;
  const unsigned short* ap0 = A + (long long)ar0 * K + (i0 & 3) * 8;
  const unsigned short* ap1 = A + (long long)ar1 * K + (i1 & 3) * 8;
  const unsigned short* bp0 = B + (long long)br0 * K + (i0 & 3) * 8;
  const unsigned short* bp1 = B + (long long)br1 * K + (i1 & 3) * 8;
  unsigned short* da0 = As + wave * 512;          // (wave*64 idx)*8 ushorts
  unsigned short* da1 = As + 2048 + wave * 512;   // (256+wave*64)*8
  unsigned short* db0 = Bs + wave * 512;
  unsigned short* db1 = Bs + 2048 + wave * 512;

  for (int k0 = 0; k0 < K; k0 += 32){
    gl_lds16(ap0, da0);
    gl_lds16(ap1, da1);
    gl_lds16(bp0, db0);
    gl_lds16(bp1, db1);
    ap0 += 32; ap1 += 32; bp0 += 32; bp1 += 32;
    __syncthreads();
    bfrag af[4], bfv[4];
#pragma unroll
    for (int m = 0; m < 4; ++m) af[m] = *(const bfrag*)&As[(wm + m*16 + fr)*32 + kg*8];
#pragma unroll
    for (int n = 0; n < 4; ++n) bfv[n] = *(const bfrag*)&Bs[(wn + n*16 + fr)*32 + kg*8];
#pragma unroll
    for (int m = 0; m < 4; ++m)
#pragma unroll
      for (int n = 0; n < 4; ++n)
        acc[m][n] = __builtin_amdgcn_mfma_f32_16x16x32_bf16(af[m], bfv[n], acc[m][n], 0, 0, 0);
    __syncthreads();
  }

  // C/D layout: col = lane&15, row = (lane>>4)*4 + reg  (m89-verified)
#pragma unroll
  for (int m = 0; m < 4; ++m){
    const int row0 = bm + wm + m*16 + kg*4;
#pragma unroll
    for (int n = 0; n < 4; ++n){
      const int col = bn + wn + n*16 + fr;
      if (col < N){
        f4 v = acc[m][n];
#pragma unroll
        for (int r = 0; r < 4; ++r){
          const int row = row0 + r;
          if (row < M){
            const long long off = cbase + (long long)row * N + col;
            if (EPI == 0)      ((unsigned short*)Cp)[off] = f2bf(v[r]);
            else if (EPI == 1) ((float*)Cp)[off] = v[r];
            else               ((float*)Cp)[off] = (v[r] + addin[off]) * 0.5f;
          }
        }
      }
    }
  }
}

// ---------------- f32 -> bf16 convert (vectorized) ----------------
__global__ void cvt_bf16(const float* __restrict__ in, unsigned short* __restrict__ out,
                         long long n4)
{
  long long i = (long long)blockIdx.x * 256 + threadIdx.x;
  if (i >= n4) return;
  float4 v = ((const float4*)in)[i];
  us4 o; o[0] = f2bf(v.x); o[1] = f2bf(v.y); o[2] = f2bf(v.z); o[3] = f2bf(v.w);
  ((us4*)out)[i] = o;
}

// ---------------- per-matrix transpose + convert: [z][R][C] f32 -> [z][C][R] bf16 ----------------
__global__ __launch_bounds__(256) void transpose_cvt(const float* __restrict__ in,
    unsigned short* __restrict__ out, int R, int C)
{
  __shared__ float tile[32][33];
  const long long z = blockIdx.z;
  const float* ip = in + z * (long long)R * C;
  unsigned short* op = out + z * (long long)R * C;
  const int r0 = blockIdx.y * 32, c0 = blockIdx.x * 32;
  const int t = threadIdx.x;
  const int lr = t >> 3, lc = (t & 7) * 4;
  float4 v = *(const float4*)(ip + (long long)(r0 + lr) * C + c0 + lc);
  tile[lr][lc+0] = v.x; tile[lr][lc+1] = v.y; tile[lr][lc+2] = v.z; tile[lr][lc+3] = v.w;
  __syncthreads();
  const int oc = t >> 3, orr = (t & 7) * 4;
  us4 o;
  o[0] = f2bf(tile[orr+0][oc]); o[1] = f2bf(tile[orr+1][oc]);
  o[2] = f2bf(tile[orr+2][oc]); o[3] = f2bf(tile[orr+3][oc]);
  *(us4*)(op + (long long)(c0 + oc) * R + r0 + orr) = o;
}

// ---------------- router: top-4, softmax gating, z-loss ----------------
__global__ void router_topk(const float* __restrict__ logits, int* __restrict__ topk,
                            float* __restrict__ gating, float* __restrict__ zout)
{
  const int t = threadIdx.x, w = t >> 6, lane = t & 63;
  const int n = blockIdx.x * 4 + w;
  const float lg = logits[(long long)n * 64 + lane];
  float z = lg * lg;
#pragma unroll
  for (int off = 32; off; off >>= 1) z += __shfl_xor(z, off);
  __shared__ float zs[4];
  if (lane == 0) zs[w] = z;
  __syncthreads();
  if (t == 0) atomicAdd(zout, (zs[0]+zs[1]+zs[2]+zs[3]) * (0.0001f / 262144.0f));

  float cur = lg;
  float tl[4]; int ti[4];
#pragma unroll
  for (int k = 0; k < 4; ++k){
    float s = cur; int si = lane;
#pragma unroll
    for (int off = 32; off; off >>= 1){
      float so = __shfl_xor(s, off); int io = __shfl_xor(si, off);
      if (so > s || (so == s && io < si)){ s = so; si = io; }
    }
    tl[k] = s; ti[k] = si;               // argmax, low-index tiebreak (matches top_k)
    if (lane == si) cur = -3.0e38f;
  }
  if (lane == 0){
    const float m0 = tl[0];
    const float e0 = __expf(tl[0]-m0), e1 = __expf(tl[1]-m0),
                e2 = __expf(tl[2]-m0), e3 = __expf(tl[3]-m0);
    const float inv = 1.0f / (e0 + e1 + e2 + e3);
    topk[n*4+0] = ti[0]; topk[n*4+1] = ti[1]; topk[n*4+2] = ti[2]; topk[n*4+3] = ti[3];
    gating[n*4+0] = e0*inv; gating[n*4+1] = e1*inv; gating[n*4+2] = e2*inv; gating[n*4+3] = e3*inv;
  }
}

// ---------------- deterministic per-expert rank scan (reproduces stable argsort order) ----------------
__global__ void scan_route(const int* __restrict__ topk, int* __restrict__ gm,
                           int* __restrict__ rev, int* __restrict__ counts)
{
  const int e = blockIdx.x;
  const int t = threadIdx.x, w = t >> 6, lane = t & 63;
  __shared__ int wtot[4];
  int running = 0;
  for (int c = 0; c < 16384; c += 256){
    const int j = c + t;
    const bool p = (topk[j] == e);
    const unsigned long long m = __ballot(p);
    const int prefix = __popcll(m & ((1ull << lane) - 1ull));
    if (lane == 0) wtot[w] = __popcll(m);
    __syncthreads();
    int woff = 0;
#pragma unroll
    for (int i = 0; i < 4; ++i){ if (i < w) woff += wtot[i]; }
    const int btot = wtot[0] + wtot[1] + wtot[2] + wtot[3];
    if (p){
      const int rank = running + woff + prefix;
      gm[j] = (rank < MAXLD) ? (e * MAXLD + rank) : NSLOT;
      if (rank < MAXLD) rev[e * MAXLD + rank] = j >> 2;   // token index
    }
    running += btot;
    __syncthreads();
  }
  if (t == 0) counts[e] = running;
}

// ---------------- gather down-projected tokens into expert slots ----------------
__global__ void gather_pad(const unsigned short* __restrict__ down, const int* __restrict__ rev,
                           const int* __restrict__ counts, unsigned short* __restrict__ pad)
{
  const int idx = blockIdx.x * 256 + threadIdx.x;     // NSLOT*64
  const int s = idx >> 6, c8 = (idx & 63) * 8;
  const int e = s / MAXLD;
  const int r = s - e * MAXLD;
  int cnt = counts[e]; if (cnt > MAXLD) cnt = MAXLD;
  us8 v = {0,0,0,0,0,0,0,0};
  if (r < cnt){
    const int tok = rev[s];
    v = *(const us8*)(down + (long long)tok * 512 + c8);
  }
  *(us8*)(pad + (long long)s * 512 + c8) = v;
}

// ---------------- silu(G)*U elementwise (strided rows, bf16x8) ----------------
__global__ void silu_mul(const unsigned short* __restrict__ G, const unsigned short* __restrict__ U,
                         unsigned short* __restrict__ O, long long ldg, long long ldu, long long ldo,
                         long long cols8, long long total)
{
  const long long idx = (long long)blockIdx.x * 256 + threadIdx.x;
  if (idx >= total) return;
  const long long rr = idx / cols8;
  const long long cc = (idx - rr * cols8) * 8;
  us8 g = *(const us8*)(G + rr * ldg + cc);
  us8 u = *(const us8*)(U + rr * ldu + cc);
  us8 o;
#pragma unroll
  for (int j = 0; j < 8; ++j){
    const float gf = bf2f(g[j]);
    const float s = gf / (1.0f + __expf(-gf));
    o[j] = f2bf(s * bf2f(u[j]));
  }
  *(us8*)(O + rr * ldo + cc) = o;
}

// ---------------- gating-weighted combine of expert outputs ----------------
__global__ void combine_moe(const unsigned short* __restrict__ po, const int* __restrict__ gm,
                            const float* __restrict__ gating, unsigned short* __restrict__ routed)
{
  const int idx = blockIdx.x * 256 + threadIdx.x;     // NTOK*64
  const int n = idx >> 6, c8 = (idx & 63) * 8;
  float acc[8] = {0,0,0,0,0,0,0,0};
#pragma unroll
  for (int k = 0; k < 4; ++k){
    const int slot = gm[n*4 + k];
    if (slot < NSLOT){
      const float gw = gating[n*4 + k];
      us8 v = *(const us8*)(po + (long long)slot * 512 + c8);
#pragma unroll
      for (int j = 0; j < 8; ++j) acc[j] += gw * bf2f(v[j]);
    }
  }
  us8 o;
#pragma unroll
  for (int j = 0; j < 8; ++j) o[j] = f2bf(acc[j]);
  *(us8*)(routed + (long long)n * 512 + c8) = o;
}

// =====================================================================
extern "C" void kernel_launch(void* const* d_in, const int* in_sizes, int n_in,
                              void* d_out, int out_size, void* d_ws, size_t ws_size,
                              hipStream_t stream)
{
  const float* x      = (const float*)d_in[0];
  const float* rw     = (const float*)d_in[1];
  const float* gate_w = (const float*)d_in[2];
  const float* up_w   = (const float*)d_in[3];
  const float* down_w = (const float*)d_in[4];
  const float* w_down = (const float*)d_in[5];
  const float* w_up   = (const float*)d_in[6];
  const float* w12    = (const float*)d_in[7];
  const float* w3     = (const float*)d_in[8];
  float* out = (float*)d_out;

  char* ws = (char*)d_ws;
  unsigned short* HBF   = (unsigned short*)(ws + 0ull);            // 16.78 MB  h bf16
  unsigned short* RWBF  = (unsigned short*)(ws + 16777216ull);     // 0.26 MB
  unsigned short* GATEB = (unsigned short*)(ws + 17039360ull);     // 33.55 MB
  unsigned short* UPB   = (unsigned short*)(ws + 50593792ull);     // 33.55 MB
  unsigned short* DWB   = (unsigned short*)(ws + 84148224ull);     // 33.55 MB down_w
  unsigned short* WDB   = (unsigned short*)(ws + 117702656ull);    // 2.10 MB  w_down
  unsigned short* WUB   = (unsigned short*)(ws + 119799808ull);    // 2.10 MB  w_up
  unsigned short* W12T  = (unsigned short*)(ws + 121896960ull);    // 201.3 MB [E][3072][512]
  unsigned short* W3T   = (unsigned short*)(ws + 323223552ull);    // 100.7 MB [E][512][1536]
  float*          LOGIT = (float*)(ws + 423886848ull);             // 1.05 MB
  int*            TOPKI = (int*)(ws + 424935424ull);               // 64 KB
  float*          GATE4 = (float*)(ws + 425000960ull);             // 64 KB
  int*            GM    = (int*)(ws + 425066496ull);               // 64 KB
  int*            CNT   = (int*)(ws + 425132032ull);               // 256 B
  int*            REV   = (int*)(ws + 425132288ull);               // 76 KB
  unsigned short* GU    = (unsigned short*)(ws + 425210112ull);    // 134.2 MB g|u ; later h12
  unsigned short* ACTS  = (unsigned short*)(ws + 559427840ull);    // 67.1 MB act_shared ; later act_exp
  float*          SHRD  = (float*)(ws + 626536704ull);             // 33.55 MB shared f32
  unsigned short* DNB   = (unsigned short*)(ws + 660091136ull);    // 4.19 MB down bf16
  unsigned short* PAD   = (unsigned short*)(ws + 664285440ull);    // 19.92 MB
  unsigned short* PO    = (unsigned short*)(ws + 684208384ull);    // 19.92 MB
  unsigned short* RTD   = (unsigned short*)(ws + 704131328ull);    // 4.19 MB  (end ~708.3 MB)

  // zero the z-loss accumulator slot (replay-safe)
  hipMemsetAsync((char*)d_out + 8388608ull * 4, 0, 4, stream);

  // bf16 conversions
  cvt_bf16<<<8192,  256, 0, stream>>>(x,      HBF,   2097152);
  cvt_bf16<<<128,   256, 0, stream>>>(rw,     RWBF,  32768);
  cvt_bf16<<<16384, 256, 0, stream>>>(gate_w, GATEB, 4194304);
  cvt_bf16<<<16384, 256, 0, stream>>>(up_w,   UPB,   4194304);
  cvt_bf16<<<16384, 256, 0, stream>>>(down_w, DWB,   4194304);
  cvt_bf16<<<1024,  256, 0, stream>>>(w_down, WDB,   262144);
  cvt_bf16<<<1024,  256, 0, stream>>>(w_up,   WUB,   262144);
  transpose_cvt<<<dim3(96,16,64), 256, 0, stream>>>(w12, W12T, 512, 3072);
  transpose_cvt<<<dim3(16,48,64), 256, 0, stream>>>(w3,  W3T,  1536, 512);

  // router: logits (f32 accum via MFMA), then top-4/gating/z-loss
  gemm_bt<1><<<dim3(1,32,1), 256, 0, stream>>>(HBF, RWBF, LOGIT, nullptr,
                                               4096, 64, 2048, 0, 0, 0);
  router_topk<<<1024, 256, 0, stream>>>(LOGIT, TOPKI, GATE4, out + 8388608);
  scan_route<<<64, 256, 0, stream>>>(TOPKI, GM, REV, CNT);

  // shared expert: g, u, silu*, down-proj
  gemm_bt<0><<<dim3(64,32,1), 256, 0, stream>>>(HBF, GATEB, GU, nullptr,
                                                4096, 8192, 2048, 0, 0, 0);
  gemm_bt<0><<<dim3(64,32,1), 256, 0, stream>>>(HBF, UPB, GU + 33554432ull, nullptr,
                                                4096, 8192, 2048, 0, 0, 0);
  silu_mul<<<16384, 256, 0, stream>>>(GU, GU + 33554432ull, ACTS, 8192, 8192, 8192,
                                      1024, 4194304);
  gemm_bt<1><<<dim3(16,32,1), 256, 0, stream>>>(ACTS, DWB, SHRD, nullptr,
                                                4096, 2048, 8192, 0, 0, 0);

  // MoE path: bottleneck down-proj, slot gather, grouped expert MLPs, combine
  gemm_bt<0><<<dim3(4,32,1), 256, 0, stream>>>(HBF, WDB, DNB, nullptr,
                                               4096, 512, 2048, 0, 0, 0);
  gather_pad<<<4864, 256, 0, stream>>>(DNB, REV, CNT, PAD);
  gemm_bt<0><<<dim3(24,3,64), 256, 0, stream>>>(PAD, W12T, GU, nullptr,
                                                304, 3072, 512, 155648, 1572864, 933888);
  silu_mul<<<14592, 256, 0, stream>>>(GU, GU + 1536, ACTS, 3072, 3072, 1536,
                                      192, 3735552);
  gemm_bt<0><<<dim3(4,3,64), 256, 0, stream>>>(ACTS, W3T, PO, nullptr,
                                               304, 512, 1536, 466944, 786432, 155648);
  combine_moe<<<1024, 256, 0, stream>>>(PO, GM, GATE4, RTD);

  // final: out = (shared + routed @ w_up^T) * 0.5
  gemm_bt<2><<<dim3(16,32,1), 256, 0, stream>>>(RTD, WUB, out, SHRD,
                                                4096, 2048, 512, 0, 0, 0);
}

// Round 2
// 1260.904 us; speedup vs baseline: 1.0672x; 1.0672x over previous
//
#include <hip/hip_runtime.h>

#define DEV __device__ __forceinline__

typedef __attribute__((ext_vector_type(4))) float f4;
typedef __attribute__((ext_vector_type(8))) __bf16 bfrag;
typedef __attribute__((ext_vector_type(4))) unsigned short us4;
typedef __attribute__((ext_vector_type(8))) unsigned short us8;

// problem constants
#define NTOK   4096
#define DMODEL 2048
#define NEXP   64
#define MAXLD  304
#define NSLOT  19456   // 64*304

DEV unsigned short f2bf(float f){
  union { float f; unsigned int i; } u; u.f = f;
  unsigned int r = u.i + 0x7fffu + ((u.i >> 16) & 1u);
  return (unsigned short)(r >> 16);
}
DEV float bf2f(unsigned short b){
  union { unsigned int i; float f; } u; u.i = ((unsigned int)b) << 16;
  return u.f;
}

DEV void gl_lds16(const unsigned short* g, unsigned short* l){
  __builtin_amdgcn_global_load_lds(
      (const __attribute__((address_space(1))) void*)g,
      (__attribute__((address_space(3))) void*)l, 16, 0, 0);
}

// ============== 256x256 pipelined GEMM: C = A @ B^T ==================
// A: M x K bf16, B: N x K bf16. Requires M%256==0, N%256==0, K%32==0, K/32>=3.
// 512 threads = 8 waves (2Mx4N), per-wave 128x64 output (8x4 16x16x32 frags).
// 3-deep LDS pipeline (96 KiB), stage 2 tiles ahead, vmcnt(4) steady state,
// one s_barrier per K-tile. LDS slot swizzle: chunk kg ^ ((row>>1)&3),
// applied on the global SOURCE (involution) so global_load_lds stays linear.
// EPI: 0 = bf16 out, 1 = f32 out
template<int EPI>
__global__ __launch_bounds__(512, 2) void gemm256(
    const unsigned short* __restrict__ A, const unsigned short* __restrict__ B,
    void* __restrict__ Cp, int M, int N, int K)
{
  __shared__ unsigned short As[3][256*32];
  __shared__ unsigned short Bs[3][256*32];

  // bijective XCD swizzle (grid size divisible by 8 at all call sites)
  const int nwg = gridDim.x * gridDim.y;
  int bid = blockIdx.y * gridDim.x + blockIdx.x;
  bid = (bid & 7) * (nwg >> 3) + (bid >> 3);
  const int bx = bid % gridDim.x, by = bid / gridDim.x;
  const int bm = by * 256, bn = bx * 256;

  const int t = threadIdx.x, lane = t & 63;
  const int wave = t >> 6;
  const int wm = (wave >> 2) * 128, wn = (wave & 3) * 64;
  const int fr = lane & 15, kg = lane >> 4;

  // per-thread staging: chunks p0=t, p1=t+512 of the 1024-chunk (256x32) tile.
  // chunk p: row=p>>2, linear slot cl=p&3; source chunk = cl ^ ((row>>1)&3).
  const int p0 = t, p1 = t + 512;
  const int ar0 = p0 >> 2, as0 = (p0 & 3) ^ ((ar0 >> 1) & 3);
  const int ar1 = p1 >> 2, as1 = (p1 & 3) ^ ((ar1 >> 1) & 3);
  const unsigned short* a0 = A + (long long)(bm + ar0) * K + as0 * 8;
  const unsigned short* a1 = A + (long long)(bm + ar1) * K + as1 * 8;
  const unsigned short* b0 = B + (long long)(bn + ar0) * K + as0 * 8;
  const unsigned short* b1 = B + (long long)(bn + ar1) * K + as1 * 8;

  f4 acc[8][4];
#pragma unroll
  for (int m = 0; m < 8; ++m)
#pragma unroll
    for (int n = 0; n < 4; ++n) acc[m][n] = f4{0.f,0.f,0.f,0.f};

  const int nt = K >> 5;

  // prologue: fully stage tiles 0 and 1
  gl_lds16(a0, &As[0][p0*8]); gl_lds16(a1, &As[0][p1*8]);
  gl_lds16(b0, &Bs[0][p0*8]); gl_lds16(b1, &Bs[0][p1*8]);
  a0 += 32; a1 += 32; b0 += 32; b1 += 32;
  gl_lds16(a0, &As[1][p0*8]); gl_lds16(a1, &As[1][p1*8]);
  gl_lds16(b0, &Bs[1][p0*8]); gl_lds16(b1, &Bs[1][p1*8]);
  a0 += 32; a1 += 32; b0 += 32; b1 += 32;
  asm volatile("s_waitcnt vmcnt(4)" ::: "memory");   // tile 0 landed
  __builtin_amdgcn_s_barrier();
  __builtin_amdgcn_sched_barrier(0);

  int cur = 0;
  for (int tt = 0; tt < nt; ++tt){
    const unsigned short* Ab = As[cur];
    const unsigned short* Bb = Bs[cur];
    const int stg = (cur >= 1) ? cur - 1 : cur + 2;     // (cur+2)%3
    const bool do_stage = (tt + 2 < nt);

    // B fragments (whole tile, reused by both phases)
    bfrag bf[4];
#pragma unroll
    for (int n = 0; n < 4; ++n){
      const int r = wn + n*16 + fr;
      bf[n] = *(const bfrag*)&Bb[r*32 + ((kg ^ ((r>>1)&3)) << 3)];
    }

    // ---- phase 0: rows 0..63 of the wave's 128 ----
    bfrag af[4];
#pragma unroll
    for (int m = 0; m < 4; ++m){
      const int r = wm + m*16 + fr;
      af[m] = *(const bfrag*)&Ab[r*32 + ((kg ^ ((r>>1)&3)) << 3)];
    }
    if (do_stage){
      gl_lds16(a0, &As[stg][p0*8]); gl_lds16(a1, &As[stg][p1*8]);
      a0 += 32; a1 += 32;
    }
    __builtin_amdgcn_s_setprio(1);
#pragma unroll
    for (int m = 0; m < 4; ++m)
#pragma unroll
      for (int n = 0; n < 4; ++n)
        acc[m][n] = __builtin_amdgcn_mfma_f32_16x16x32_bf16(af[m], bf[n], acc[m][n], 0, 0, 0);
    __builtin_amdgcn_s_setprio(0);

    // ---- phase 1: rows 64..127 ----
#pragma unroll
    for (int m = 0; m < 4; ++m){
      const int r = wm + 64 + m*16 + fr;
      af[m] = *(const bfrag*)&Ab[r*32 + ((kg ^ ((r>>1)&3)) << 3)];
    }
    if (do_stage){
      gl_lds16(b0, &Bs[stg][p0*8]); gl_lds16(b1, &Bs[stg][p1*8]);
      b0 += 32; b1 += 32;
    }
    __builtin_amdgcn_s_setprio(1);
#pragma unroll
    for (int m = 0; m < 4; ++m)
#pragma unroll
      for (int n = 0; n < 4; ++n)
        acc[4+m][n] = __builtin_amdgcn_mfma_f32_16x16x32_bf16(af[m], bf[n], acc[4+m][n], 0, 0, 0);
    __builtin_amdgcn_s_setprio(0);

    // ---- tile boundary ----
    __builtin_amdgcn_sched_barrier(0);
    if (tt + 2 < nt){
      asm volatile("s_waitcnt vmcnt(4)" ::: "memory");  // tile tt+1 landed
    } else if (tt + 1 < nt){
      asm volatile("s_waitcnt vmcnt(0)" ::: "memory");  // final drain
    }
    if (tt + 1 < nt){
      __builtin_amdgcn_s_barrier();
      __builtin_amdgcn_sched_barrier(0);
    }
    cur = (cur == 2) ? 0 : cur + 1;
  }

  // epilogue: C/D layout col=lane&15, row=(lane>>4)*4+reg
#pragma unroll
  for (int m = 0; m < 8; ++m){
    const int row0 = bm + wm + m*16 + kg*4;
#pragma unroll
    for (int n = 0; n < 4; ++n){
      const int col = bn + wn + n*16 + fr;
      f4 v = acc[m][n];
#pragma unroll
      for (int r = 0; r < 4; ++r){
        const long long off = (long long)(row0 + r) * N + col;
        if (EPI == 0) ((unsigned short*)Cp)[off] = f2bf(v[r]);
        else          ((float*)Cp)[off] = v[r];
      }
    }
  }
}

// ---------------- generic 128x128 C = A @ B^T GEMM (bounds-checked) --------
// EPI: 0 = bf16 out, 1 = f32 out, 2 = f32 out = (acc + addin)*0.5
template<int EPI>
__global__ __launch_bounds__(256) void gemm_bt(
    const unsigned short* __restrict__ A, const unsigned short* __restrict__ B,
    void* __restrict__ Cp, const float* __restrict__ addin,
    int M, int N, int K, long long sA, long long sB, long long sC)
{
  __shared__ unsigned short As[128*32];
  __shared__ unsigned short Bs[128*32];
  A += (long long)blockIdx.z * sA;
  B += (long long)blockIdx.z * sB;
  const long long cbase = (long long)blockIdx.z * sC;
  const int bm = blockIdx.y * 128, bn = blockIdx.x * 128;
  const int t = threadIdx.x, wave = t >> 6, lane = t & 63;
  const int wm = (wave >> 1) * 64, wn = (wave & 1) * 64;
  const int fr = lane & 15, kg = lane >> 4;

  f4 acc[4][4];
#pragma unroll
  for (int m = 0; m < 4; ++m)
#pragma unroll
    for (int n = 0; n < 4; ++n)
      acc[m][n] = f4{0.f, 0.f, 0.f, 0.f};

  const int i0 = t, i1 = 256 + t;
  int ar0 = bm + (i0 >> 2); if (ar0 > M - 1) ar0 = M - 1;
  int ar1 = bm + (i1 >> 2); if (ar1 > M - 1) ar1 = M - 1;
  int br0 = bn + (i0 >> 2); if (br0 > N - 1) br0 = N - 1;
  int br1 = bn + (i1 >> 2); if (br1 > N - 1) br1 = N - 1;
  const unsigned short* ap0 = A + (long long)ar0 * K + (i0 & 3) * 8;
  const unsigned short* ap1 = A + (long long)ar1 * K + (i1 & 3) * 8;
  const unsigned short* bp0 = B + (long long)br0 * K + (i0 & 3) * 8;
  const unsigned short* bp1 = B + (long long)br1 * K + (i1 & 3) * 8;
  unsigned short* da0 = As + wave * 512;
  unsigned short* da1 = As + 2048 + wave * 512;
  unsigned short* db0 = Bs + wave * 512;
  unsigned short* db1 = Bs + 2048 + wave * 512;

  for (int k0 = 0; k0 < K; k0 += 32){
    gl_lds16(ap0, da0);
    gl_lds16(ap1, da1);
    gl_lds16(bp0, db0);
    gl_lds16(bp1, db1);
    ap0 += 32; ap1 += 32; bp0 += 32; bp1 += 32;
    __syncthreads();
    bfrag af[4], bfv[4];
#pragma unroll
    for (int m = 0; m < 4; ++m) af[m] = *(const bfrag*)&As[(wm + m*16 + fr)*32 + kg*8];
#pragma unroll
    for (int n = 0; n < 4; ++n) bfv[n] = *(const bfrag*)&Bs[(wn + n*16 + fr)*32 + kg*8];
#pragma unroll
    for (int m = 0; m < 4; ++m)
#pragma unroll
      for (int n = 0; n < 4; ++n)
        acc[m][n] = __builtin_amdgcn_mfma_f32_16x16x32_bf16(af[m], bfv[n], acc[m][n], 0, 0, 0);
    __syncthreads();
  }

#pragma unroll
  for (int m = 0; m < 4; ++m){
    const int row0 = bm + wm + m*16 + kg*4;
#pragma unroll
    for (int n = 0; n < 4; ++n){
      const int col = bn + wn + n*16 + fr;
      if (col < N){
        f4 v = acc[m][n];
#pragma unroll
        for (int r = 0; r < 4; ++r){
          const int row = row0 + r;
          if (row < M){
            const long long off = cbase + (long long)row * N + col;
            if (EPI == 0)      ((unsigned short*)Cp)[off] = f2bf(v[r]);
            else if (EPI == 1) ((float*)Cp)[off] = v[r];
            else               ((float*)Cp)[off] = (v[r] + addin[off]) * 0.5f;
          }
        }
      }
    }
  }
}

// ---------------- f32 -> bf16 convert (vectorized) ----------------
__global__ void cvt_bf16(const float* __restrict__ in, unsigned short* __restrict__ out,
                         long long n4)
{
  long long i = (long long)blockIdx.x * 256 + threadIdx.x;
  if (i >= n4) return;
  float4 v = ((const float4*)in)[i];
  us4 o; o[0] = f2bf(v.x); o[1] = f2bf(v.y); o[2] = f2bf(v.z); o[3] = f2bf(v.w);
  ((us4*)out)[i] = o;
}

// ---------------- [z][R][C] f32 -> [z][C][R] bf16 ----------------
__global__ __launch_bounds__(256) void transpose_cvt(const float* __restrict__ in,
    unsigned short* __restrict__ out, int R, int C)
{
  __shared__ float tile[32][33];
  const long long z = blockIdx.z;
  const float* ip = in + z * (long long)R * C;
  unsigned short* op = out + z * (long long)R * C;
  const int r0 = blockIdx.y * 32, c0 = blockIdx.x * 32;
  const int t = threadIdx.x;
  const int lr = t >> 3, lc = (t & 7) * 4;
  float4 v = *(const float4*)(ip + (long long)(r0 + lr) * C + c0 + lc);
  tile[lr][lc+0] = v.x; tile[lr][lc+1] = v.y; tile[lr][lc+2] = v.z; tile[lr][lc+3] = v.w;
  __syncthreads();
  const int oc = t >> 3, orr = (t & 7) * 4;
  us4 o;
  o[0] = f2bf(tile[orr+0][oc]); o[1] = f2bf(tile[orr+1][oc]);
  o[2] = f2bf(tile[orr+2][oc]); o[3] = f2bf(tile[orr+3][oc]);
  *(us4*)(op + (long long)(c0 + oc) * R + r0 + orr) = o;
}

// ---------------- router: top-4, softmax gating, z-loss ----------------
__global__ void router_topk(const float* __restrict__ logits, int* __restrict__ topk,
                            float* __restrict__ gating, float* __restrict__ zout)
{
  const int t = threadIdx.x, w = t >> 6, lane = t & 63;
  const int n = blockIdx.x * 4 + w;
  const float lg = logits[(long long)n * 64 + lane];
  float z = lg * lg;
#pragma unroll
  for (int off = 32; off; off >>= 1) z += __shfl_xor(z, off);
  __shared__ float zs[4];
  if (lane == 0) zs[w] = z;
  __syncthreads();
  if (t == 0) atomicAdd(zout, (zs[0]+zs[1]+zs[2]+zs[3]) * (0.0001f / 262144.0f));

  float cur = lg;
  float tl[4]; int ti[4];
#pragma unroll
  for (int k = 0; k < 4; ++k){
    float s = cur; int si = lane;
#pragma unroll
    for (int off = 32; off; off >>= 1){
      float so = __shfl_xor(s, off); int io = __shfl_xor(si, off);
      if (so > s || (so == s && io < si)){ s = so; si = io; }
    }
    tl[k] = s; ti[k] = si;
    if (lane == si) cur = -3.0e38f;
  }
  if (lane == 0){
    const float m0 = tl[0];
    const float e0 = __expf(tl[0]-m0), e1 = __expf(tl[1]-m0),
                e2 = __expf(tl[2]-m0), e3 = __expf(tl[3]-m0);
    const float inv = 1.0f / (e0 + e1 + e2 + e3);
    topk[n*4+0] = ti[0]; topk[n*4+1] = ti[1]; topk[n*4+2] = ti[2]; topk[n*4+3] = ti[3];
    gating[n*4+0] = e0*inv; gating[n*4+1] = e1*inv; gating[n*4+2] = e2*inv; gating[n*4+3] = e3*inv;
  }
}

// ---------------- deterministic per-expert rank scan ----------------
__global__ void scan_route(const int* __restrict__ topk, int* __restrict__ gm,
                           int* __restrict__ rev, int* __restrict__ counts)
{
  const int e = blockIdx.x;
  const int t = threadIdx.x, w = t >> 6, lane = t & 63;
  __shared__ int wtot[4];
  int running = 0;
  for (int c = 0; c < 16384; c += 256){
    const int j = c + t;
    const bool p = (topk[j] == e);
    const unsigned long long m = __ballot(p);
    const int prefix = __popcll(m & ((1ull << lane) - 1ull));
    if (lane == 0) wtot[w] = __popcll(m);
    __syncthreads();
    int woff = 0;
#pragma unroll
    for (int i = 0; i < 4; ++i){ if (i < w) woff += wtot[i]; }
    const int btot = wtot[0] + wtot[1] + wtot[2] + wtot[3];
    if (p){
      const int rank = running + woff + prefix;
      gm[j] = (rank < MAXLD) ? (e * MAXLD + rank) : NSLOT;
      if (rank < MAXLD) rev[e * MAXLD + rank] = j >> 2;
    }
    running += btot;
    __syncthreads();
  }
  if (t == 0) counts[e] = running;
}

// ---------------- gather down-projected tokens into expert slots ----------------
__global__ void gather_pad(const unsigned short* __restrict__ down, const int* __restrict__ rev,
                           const int* __restrict__ counts, unsigned short* __restrict__ pad)
{
  const int idx = blockIdx.x * 256 + threadIdx.x;
  const int s = idx >> 6, c8 = (idx & 63) * 8;
  const int e = s / MAXLD;
  const int r = s - e * MAXLD;
  int cnt = counts[e]; if (cnt > MAXLD) cnt = MAXLD;
  us8 v = {0,0,0,0,0,0,0,0};
  if (r < cnt){
    const int tok = rev[s];
    v = *(const us8*)(down + (long long)tok * 512 + c8);
  }
  *(us8*)(pad + (long long)s * 512 + c8) = v;
}

// ---------------- silu(G)*U elementwise ----------------
__global__ void silu_mul(const unsigned short* __restrict__ G, const unsigned short* __restrict__ U,
                         unsigned short* __restrict__ O, long long ldg, long long ldu, long long ldo,
                         long long cols8, long long total)
{
  const long long idx = (long long)blockIdx.x * 256 + threadIdx.x;
  if (idx >= total) return;
  const long long rr = idx / cols8;
  const long long cc = (idx - rr * cols8) * 8;
  us8 g = *(const us8*)(G + rr * ldg + cc);
  us8 u = *(const us8*)(U + rr * ldu + cc);
  us8 o;
#pragma unroll
  for (int j = 0; j < 8; ++j){
    const float gf = bf2f(g[j]);
    const float s = gf / (1.0f + __expf(-gf));
    o[j] = f2bf(s * bf2f(u[j]));
  }
  *(us8*)(O + rr * ldo + cc) = o;
}

// ---------------- gating-weighted combine ----------------
__global__ void combine_moe(const unsigned short* __restrict__ po, const int* __restrict__ gm,
                            const float* __restrict__ gating, unsigned short* __restrict__ routed)
{
  const int idx = blockIdx.x * 256 + threadIdx.x;
  const int n = idx >> 6, c8 = (idx & 63) * 8;
  float acc[8] = {0,0,0,0,0,0,0,0};
#pragma unroll
  for (int k = 0; k < 4; ++k){
    const int slot = gm[n*4 + k];
    if (slot < NSLOT){
      const float gw = gating[n*4 + k];
      us8 v = *(const us8*)(po + (long long)slot * 512 + c8);
#pragma unroll
      for (int j = 0; j < 8; ++j) acc[j] += gw * bf2f(v[j]);
    }
  }
  us8 o;
#pragma unroll
  for (int j = 0; j < 8; ++j) o[j] = f2bf(acc[j]);
  *(us8*)(routed + (long long)n * 512 + c8) = o;
}

// =====================================================================
extern "C" void kernel_launch(void* const* d_in, const int* in_sizes, int n_in,
                              void* d_out, int out_size, void* d_ws, size_t ws_size,
                              hipStream_t stream)
{
  const float* x      = (const float*)d_in[0];
  const float* rw     = (const float*)d_in[1];
  const float* gate_w = (const float*)d_in[2];
  const float* up_w   = (const float*)d_in[3];
  const float* down_w = (const float*)d_in[4];
  const float* w_down = (const float*)d_in[5];
  const float* w_up   = (const float*)d_in[6];
  const float* w12    = (const float*)d_in[7];
  const float* w3     = (const float*)d_in[8];
  float* out = (float*)d_out;

  char* ws = (char*)d_ws;
  unsigned short* HBF   = (unsigned short*)(ws + 0ull);
  unsigned short* RWBF  = (unsigned short*)(ws + 16777216ull);
  unsigned short* GATEB = (unsigned short*)(ws + 17039360ull);
  unsigned short* UPB   = (unsigned short*)(ws + 50593792ull);
  unsigned short* DWB   = (unsigned short*)(ws + 84148224ull);
  unsigned short* WDB   = (unsigned short*)(ws + 117702656ull);
  unsigned short* WUB   = (unsigned short*)(ws + 119799808ull);
  unsigned short* W12T  = (unsigned short*)(ws + 121896960ull);
  unsigned short* W3T   = (unsigned short*)(ws + 323223552ull);
  float*          LOGIT = (float*)(ws + 423886848ull);
  int*            TOPKI = (int*)(ws + 424935424ull);
  float*          GATE4 = (float*)(ws + 425000960ull);
  int*            GM    = (int*)(ws + 425066496ull);
  int*            CNT   = (int*)(ws + 425132032ull);
  int*            REV   = (int*)(ws + 425132288ull);
  unsigned short* GU    = (unsigned short*)(ws + 425210112ull);
  unsigned short* ACTS  = (unsigned short*)(ws + 559427840ull);
  float*          SHRD  = (float*)(ws + 626536704ull);
  unsigned short* DNB   = (unsigned short*)(ws + 660091136ull);
  unsigned short* PAD   = (unsigned short*)(ws + 664285440ull);
  unsigned short* PO    = (unsigned short*)(ws + 684208384ull);
  unsigned short* RTD   = (unsigned short*)(ws + 704131328ull);

  hipMemsetAsync((char*)d_out + 8388608ull * 4, 0, 4, stream);

  // bf16 conversions
  cvt_bf16<<<8192,  256, 0, stream>>>(x,      HBF,   2097152);
  cvt_bf16<<<128,   256, 0, stream>>>(rw,     RWBF,  32768);
  cvt_bf16<<<16384, 256, 0, stream>>>(gate_w, GATEB, 4194304);
  cvt_bf16<<<16384, 256, 0, stream>>>(up_w,   UPB,   4194304);
  cvt_bf16<<<16384, 256, 0, stream>>>(down_w, DWB,   4194304);
  cvt_bf16<<<1024,  256, 0, stream>>>(w_down, WDB,   262144);
  cvt_bf16<<<1024,  256, 0, stream>>>(w_up,   WUB,   262144);
  transpose_cvt<<<dim3(96,16,64), 256, 0, stream>>>(w12, W12T, 512, 3072);
  transpose_cvt<<<dim3(16,48,64), 256, 0, stream>>>(w3,  W3T,  1536, 512);

  // router
  gemm_bt<1><<<dim3(1,32,1), 256, 0, stream>>>(HBF, RWBF, LOGIT, nullptr,
                                               4096, 64, 2048, 0, 0, 0);
  router_topk<<<1024, 256, 0, stream>>>(LOGIT, TOPKI, GATE4, out + 8388608);
  scan_route<<<64, 256, 0, stream>>>(TOPKI, GM, REV, CNT);

  // shared expert (256x256 pipelined GEMMs)
  gemm256<0><<<dim3(32,16), 512, 0, stream>>>(HBF, GATEB, GU, 4096, 8192, 2048);
  gemm256<0><<<dim3(32,16), 512, 0, stream>>>(HBF, UPB, GU + 33554432ull, 4096, 8192, 2048);
  silu_mul<<<16384, 256, 0, stream>>>(GU, GU + 33554432ull, ACTS, 8192, 8192, 8192,
                                      1024, 4194304);
  gemm256<1><<<dim3(8,16), 512, 0, stream>>>(ACTS, DWB, SHRD, 4096, 2048, 8192);

  // MoE path
  gemm_bt<0><<<dim3(4,32,1), 256, 0, stream>>>(HBF, WDB, DNB, nullptr,
                                               4096, 512, 2048, 0, 0, 0);
  gather_pad<<<4864, 256, 0, stream>>>(DNB, REV, CNT, PAD);
  gemm_bt<0><<<dim3(24,3,64), 256, 0, stream>>>(PAD, W12T, GU, nullptr,
                                                304, 3072, 512, 155648, 1572864, 933888);
  silu_mul<<<14592, 256, 0, stream>>>(GU, GU + 1536, ACTS, 3072, 3072, 1536,
                                      192, 3735552);
  gemm_bt<0><<<dim3(4,3,64), 256, 0, stream>>>(ACTS, W3T, PO, nullptr,
                                               304, 512, 1536, 466944, 786432, 155648);
  combine_moe<<<1024, 256, 0, stream>>>(PO, GM, GATE4, RTD);

  // final: out = (shared + routed @ w_up^T) * 0.5
  gemm_bt<2><<<dim3(16,32,1), 256, 0, stream>>>(RTD, WUB, out, SHRD,
                                                4096, 2048, 512, 0, 0, 0);
}

// Round 3
// 1210.888 us; speedup vs baseline: 1.1113x; 1.0413x over previous
//
#include <hip/hip_runtime.h>

#define DEV __device__ __forceinline__

typedef __attribute__((ext_vector_type(4))) float f4;
typedef __attribute__((ext_vector_type(8))) __bf16 bfrag;
typedef __attribute__((ext_vector_type(4))) unsigned short us4;
typedef __attribute__((ext_vector_type(8))) unsigned short us8;

// problem constants
#define NTOK   4096
#define DMODEL 2048
#define NEXP   64
#define MAXLD  304
#define NSLOT  19456   // 64*304

DEV unsigned short f2bf(float f){
  union { float f; unsigned int i; } u; u.f = f;
  unsigned int r = u.i + 0x7fffu + ((u.i >> 16) & 1u);
  return (unsigned short)(r >> 16);
}
DEV float bf2f(unsigned short b){
  union { unsigned int i; float f; } u; u.i = ((unsigned int)b) << 16;
  return u.f;
}

DEV void gl_lds16(const unsigned short* g, unsigned short* l){
  __builtin_amdgcn_global_load_lds(
      (const __attribute__((address_space(1))) void*)g,
      (__attribute__((address_space(3))) void*)l, 16, 0, 0);
}

// ============== 8-phase counted-vmcnt GEMM: C = A @ B^T =============
// A: M x BM-mult, B: N x K (row-major, both K-contig). BN fixed 256.
// 512 threads = 8 waves (2M x 4N). Wave tile (BM/2) x 64.
// BK=64 split in two k-halves (ks=0,1). 2 LDS K-tile buffers.
// Per K-tile 4 phases: {ds_read subtile; stage 1 half-tile; barrier;
// lgkmcnt(0); setprio(1); MFMA cluster; setprio(0); barrier}, counted
// vmcnt only at phases 2 and 4. Staging of tile t+1 goes into buf^1
// (holds tile t-1, fully consumed) -> WAR-free.
// LDS swizzle: k-chunk kg ^ ((row>>1)&3), involution applied on the
// global source so global_load_lds dest stays linear (measured: 0 conflicts).
// EPI: 0 = bf16 out, 1 = f32 out, 2 = f32 out = (acc + addin)*0.5
template<int BM, int EPI>
__global__ __launch_bounds__(512, 2) void gemm8p(
    const unsigned short* __restrict__ A, const unsigned short* __restrict__ B,
    void* __restrict__ Cp, const float* __restrict__ addin, int M, int N, int K)
{
  constexpr int FM  = BM / 32;     // A frags per wave (8 or 4)
  constexpr int HV  = FM / 2;      // A frags per phase
  constexpr int ALD = BM / 128;    // A gl_lds16 per thread per half-K (2 or 1)
  __shared__ unsigned short As[2][2][BM * 32];
  __shared__ unsigned short Bs[2][2][256 * 32];

  // bijective XCD swizzle (all call-site grids are multiples of 8)
  const int nwg = gridDim.x * gridDim.y;
  int bid = blockIdx.y * gridDim.x + blockIdx.x;
  bid = (bid & 7) * (nwg >> 3) + (bid >> 3);
  const int bx = bid % gridDim.x, by = bid / gridDim.x;
  const int bm = by * BM, bn = bx * 256;

  const int t = threadIdx.x, lane = t & 63, wave = t >> 6;
  const int wm = (wave >> 2) * (BM / 2), wn = (wave & 3) * 64;
  const int fr = lane & 15, kg = lane >> 4;

  // staging: chunk c covers LDS bytes [c*16, c*16+16) = row c>>2, k-slot c&3.
  // source k-chunk = (c&3) ^ ((c>>3)&3)  (same for c and c+512).
  const int sw = ((t >> 3) & 3) ^ (t & 3);
  const unsigned short* a_src0 = A + (long long)(bm + (t >> 2)) * K + sw * 8;
  const unsigned short* a_src1 = A + (long long)(bm + (t >> 2) + 128) * K + sw * 8;
  const unsigned short* b_src0 = B + (long long)(bn + (t >> 2)) * K + sw * 8;
  const unsigned short* b_src1 = B + (long long)(bn + (t >> 2) + 128) * K + sw * 8;
  const int wch = wave * 64;   // wave-uniform LDS chunk base (HW adds lane*16B)

#define STG_A(bufv, ksv, koff) do { \
    gl_lds16(a_src0 + (koff) + (ksv) * 32, &As[bufv][ksv][wch * 8]); \
    if (ALD == 2) gl_lds16(a_src1 + (koff) + (ksv) * 32, &As[bufv][ksv][(512 + wch) * 8]); \
  } while (0)
#define STG_B(bufv, ksv, koff) do { \
    gl_lds16(b_src0 + (koff) + (ksv) * 32, &Bs[bufv][ksv][wch * 8]); \
    gl_lds16(b_src1 + (koff) + (ksv) * 32, &Bs[bufv][ksv][(512 + wch) * 8]); \
  } while (0)
#define WAIT_LPT() do { if (ALD == 2) asm volatile("s_waitcnt vmcnt(4)" ::: "memory"); \
                        else          asm volatile("s_waitcnt vmcnt(3)" ::: "memory"); } while (0)
#define WAIT_ZERO() asm volatile("s_waitcnt vmcnt(0)" ::: "memory")
#define LGKM0() do { asm volatile("s_waitcnt lgkmcnt(0)" ::: "memory"); \
                     __builtin_amdgcn_sched_barrier(0); } while (0)

  f4 acc[FM][4];
#pragma unroll
  for (int m = 0; m < FM; ++m)
#pragma unroll
    for (int n = 0; n < 4; ++n) acc[m][n] = f4{0.f, 0.f, 0.f, 0.f};

  const int nt = K >> 6;

  // prologue: stage K-tile 0 (order: A-ks0, B-ks0, A-ks1, B-ks1)
  STG_A(0, 0, 0); STG_B(0, 0, 0); STG_A(0, 1, 0); STG_B(0, 1, 0);
  WAIT_LPT();                       // ks0 of tile 0 landed
  __builtin_amdgcn_s_barrier();
  __builtin_amdgcn_sched_barrier(0);

  int buf = 0;
  for (int tt = 0; tt < nt; ++tt){
    const long long ko = (long long)(tt + 1) * 64;
    const bool stg = (tt + 1 < nt);
    const int nb = buf ^ 1;
    bfrag bfv[4], af[HV];

    // ---- phase 0: ks=0, m-half 0 ----
#pragma unroll
    for (int n = 0; n < 4; ++n){
      const int r = wn + n * 16 + fr;
      bfv[n] = *(const bfrag*)&Bs[buf][0][r * 32 + ((kg ^ ((r >> 1) & 3)) << 3)];
    }
#pragma unroll
    for (int m = 0; m < HV; ++m){
      const int r = wm + m * 16 + fr;
      af[m] = *(const bfrag*)&As[buf][0][r * 32 + ((kg ^ ((r >> 1) & 3)) << 3)];
    }
    if (stg) STG_A(nb, 0, ko);
    __builtin_amdgcn_s_barrier();
    LGKM0();
    __builtin_amdgcn_s_setprio(1);
#pragma unroll
    for (int m = 0; m < HV; ++m)
#pragma unroll
      for (int n = 0; n < 4; ++n)
        acc[m][n] = __builtin_amdgcn_mfma_f32_16x16x32_bf16(af[m], bfv[n], acc[m][n], 0, 0, 0);
    __builtin_amdgcn_s_setprio(0);
    __builtin_amdgcn_s_barrier();

    // ---- phase 1: ks=0, m-half 1 ----
#pragma unroll
    for (int m = 0; m < HV; ++m){
      const int r = wm + HV * 16 + m * 16 + fr;
      af[m] = *(const bfrag*)&As[buf][0][r * 32 + ((kg ^ ((r >> 1) & 3)) << 3)];
    }
    if (stg) STG_B(nb, 0, ko);
    __builtin_amdgcn_s_barrier();
    LGKM0();
    __builtin_amdgcn_s_setprio(1);
#pragma unroll
    for (int m = 0; m < HV; ++m)
#pragma unroll
      for (int n = 0; n < 4; ++n)
        acc[HV + m][n] = __builtin_amdgcn_mfma_f32_16x16x32_bf16(af[m], bfv[n], acc[HV + m][n], 0, 0, 0);
    __builtin_amdgcn_s_setprio(0);
    if (stg) WAIT_LPT(); else WAIT_ZERO();   // ks1 of tile tt landed
    __builtin_amdgcn_s_barrier();
    __builtin_amdgcn_sched_barrier(0);

    // ---- phase 2: ks=1, m-half 0 ----
#pragma unroll
    for (int n = 0; n < 4; ++n){
      const int r = wn + n * 16 + fr;
      bfv[n] = *(const bfrag*)&Bs[buf][1][r * 32 + ((kg ^ ((r >> 1) & 3)) << 3)];
    }
#pragma unroll
    for (int m = 0; m < HV; ++m){
      const int r = wm + m * 16 + fr;
      af[m] = *(const bfrag*)&As[buf][1][r * 32 + ((kg ^ ((r >> 1) & 3)) << 3)];
    }
    if (stg) STG_A(nb, 1, ko);
    __builtin_amdgcn_s_barrier();
    LGKM0();
    __builtin_amdgcn_s_setprio(1);
#pragma unroll
    for (int m = 0; m < HV; ++m)
#pragma unroll
      for (int n = 0; n < 4; ++n)
        acc[m][n] = __builtin_amdgcn_mfma_f32_16x16x32_bf16(af[m], bfv[n], acc[m][n], 0, 0, 0);
    __builtin_amdgcn_s_setprio(0);
    __builtin_amdgcn_s_barrier();

    // ---- phase 3: ks=1, m-half 1 ----
#pragma unroll
    for (int m = 0; m < HV; ++m){
      const int r = wm + HV * 16 + m * 16 + fr;
      af[m] = *(const bfrag*)&As[buf][1][r * 32 + ((kg ^ ((r >> 1) & 3)) << 3)];
    }
    if (stg) STG_B(nb, 1, ko);
    __builtin_amdgcn_s_barrier();
    LGKM0();
    __builtin_amdgcn_s_setprio(1);
#pragma unroll
    for (int m = 0; m < HV; ++m)
#pragma unroll
      for (int n = 0; n < 4; ++n)
        acc[HV + m][n] = __builtin_amdgcn_mfma_f32_16x16x32_bf16(af[m], bfv[n], acc[HV + m][n], 0, 0, 0);
    __builtin_amdgcn_s_setprio(0);
    if (stg) WAIT_LPT();                     // ks0 of tile tt+1 landed
    __builtin_amdgcn_s_barrier();
    __builtin_amdgcn_sched_barrier(0);

    buf = nb;
  }

  // epilogue: C/D layout col=lane&15, row=(lane>>4)*4+reg
#pragma unroll
  for (int m = 0; m < FM; ++m){
    const int row0 = bm + wm + m * 16 + kg * 4;
#pragma unroll
    for (int n = 0; n < 4; ++n){
      const int col = bn + wn + n * 16 + fr;
      f4 v = acc[m][n];
#pragma unroll
      for (int r = 0; r < 4; ++r){
        const long long off = (long long)(row0 + r) * N + col;
        if (EPI == 0)      ((unsigned short*)Cp)[off] = f2bf(v[r]);
        else if (EPI == 1) ((float*)Cp)[off] = v[r];
        else               ((float*)Cp)[off] = (v[r] + addin[off]) * 0.5f;
      }
    }
  }
#undef STG_A
#undef STG_B
#undef WAIT_LPT
#undef WAIT_ZERO
#undef LGKM0
}

// ---------------- generic 128x128 C = A @ B^T GEMM (bounds-checked) --------
// EPI: 0 = bf16 out, 1 = f32 out, 2 = f32 out = (acc + addin)*0.5
template<int EPI>
__global__ __launch_bounds__(256) void gemm_bt(
    const unsigned short* __restrict__ A, const unsigned short* __restrict__ B,
    void* __restrict__ Cp, const float* __restrict__ addin,
    int M, int N, int K, long long sA, long long sB, long long sC)
{
  __shared__ unsigned short As[128*32];
  __shared__ unsigned short Bs[128*32];
  A += (long long)blockIdx.z * sA;
  B += (long long)blockIdx.z * sB;
  const long long cbase = (long long)blockIdx.z * sC;
  const int bm = blockIdx.y * 128, bn = blockIdx.x * 128;
  const int t = threadIdx.x, wave = t >> 6, lane = t & 63;
  const int wm = (wave >> 1) * 64, wn = (wave & 1) * 64;
  const int fr = lane & 15, kg = lane >> 4;

  f4 acc[4][4];
#pragma unroll
  for (int m = 0; m < 4; ++m)
#pragma unroll
    for (int n = 0; n < 4; ++n)
      acc[m][n] = f4{0.f, 0.f, 0.f, 0.f};

  const int i0 = t, i1 = 256 + t;
  int ar0 = bm + (i0 >> 2); if (ar0 > M - 1) ar0 = M - 1;
  int ar1 = bm + (i1 >> 2); if (ar1 > M - 1) ar1 = M - 1;
  int br0 = bn + (i0 >> 2); if (br0 > N - 1) br0 = N - 1;
  int br1 = bn + (i1 >> 2); if (br1 > N - 1) br1 = N - 1;
  const unsigned short* ap0 = A + (long long)ar0 * K + (i0 & 3) * 8;
  const unsigned short* ap1 = A + (long long)ar1 * K + (i1 & 3) * 8;
  const unsigned short* bp0 = B + (long long)br0 * K + (i0 & 3) * 8;
  const unsigned short* bp1 = B + (long long)br1 * K + (i1 & 3) * 8;
  unsigned short* da0 = As + wave * 512;
  unsigned short* da1 = As + 2048 + wave * 512;
  unsigned short* db0 = Bs + wave * 512;
  unsigned short* db1 = Bs + 2048 + wave * 512;

  for (int k0 = 0; k0 < K; k0 += 32){
    gl_lds16(ap0, da0);
    gl_lds16(ap1, da1);
    gl_lds16(bp0, db0);
    gl_lds16(bp1, db1);
    ap0 += 32; ap1 += 32; bp0 += 32; bp1 += 32;
    __syncthreads();
    bfrag af[4], bfv[4];
#pragma unroll
    for (int m = 0; m < 4; ++m) af[m] = *(const bfrag*)&As[(wm + m*16 + fr)*32 + kg*8];
#pragma unroll
    for (int n = 0; n < 4; ++n) bfv[n] = *(const bfrag*)&Bs[(wn + n*16 + fr)*32 + kg*8];
#pragma unroll
    for (int m = 0; m < 4; ++m)
#pragma unroll
      for (int n = 0; n < 4; ++n)
        acc[m][n] = __builtin_amdgcn_mfma_f32_16x16x32_bf16(af[m], bfv[n], acc[m][n], 0, 0, 0);
    __syncthreads();
  }

#pragma unroll
  for (int m = 0; m < 4; ++m){
    const int row0 = bm + wm + m*16 + kg*4;
#pragma unroll
    for (int n = 0; n < 4; ++n){
      const int col = bn + wn + n*16 + fr;
      if (col < N){
        f4 v = acc[m][n];
#pragma unroll
        for (int r = 0; r < 4; ++r){
          const int row = row0 + r;
          if (row < M){
            const long long off = cbase + (long long)row * N + col;
            if (EPI == 0)      ((unsigned short*)Cp)[off] = f2bf(v[r]);
            else if (EPI == 1) ((float*)Cp)[off] = v[r];
            else               ((float*)Cp)[off] = (v[r] + addin[off]) * 0.5f;
          }
        }
      }
    }
  }
}

// ---------------- f32 -> bf16 convert (vectorized) ----------------
__global__ void cvt_bf16(const float* __restrict__ in, unsigned short* __restrict__ out,
                         long long n4)
{
  long long i = (long long)blockIdx.x * 256 + threadIdx.x;
  if (i >= n4) return;
  float4 v = ((const float4*)in)[i];
  us4 o; o[0] = f2bf(v.x); o[1] = f2bf(v.y); o[2] = f2bf(v.z); o[3] = f2bf(v.w);
  ((us4*)out)[i] = o;
}

// ---------------- [z][R][C] f32 -> [z][C][R] bf16 ----------------
__global__ __launch_bounds__(256) void transpose_cvt(const float* __restrict__ in,
    unsigned short* __restrict__ out, int R, int C)
{
  __shared__ float tile[32][33];
  const long long z = blockIdx.z;
  const float* ip = in + z * (long long)R * C;
  unsigned short* op = out + z * (long long)R * C;
  const int r0 = blockIdx.y * 32, c0 = blockIdx.x * 32;
  const int t = threadIdx.x;
  const int lr = t >> 3, lc = (t & 7) * 4;
  float4 v = *(const float4*)(ip + (long long)(r0 + lr) * C + c0 + lc);
  tile[lr][lc+0] = v.x; tile[lr][lc+1] = v.y; tile[lr][lc+2] = v.z; tile[lr][lc+3] = v.w;
  __syncthreads();
  const int oc = t >> 3, orr = (t & 7) * 4;
  us4 o;
  o[0] = f2bf(tile[orr+0][oc]); o[1] = f2bf(tile[orr+1][oc]);
  o[2] = f2bf(tile[orr+2][oc]); o[3] = f2bf(tile[orr+3][oc]);
  *(us4*)(op + (long long)(c0 + oc) * R + r0 + orr) = o;
}

// ---------------- router: top-4, softmax gating, z-loss ----------------
__global__ void router_topk(const float* __restrict__ logits, int* __restrict__ topk,
                            float* __restrict__ gating, float* __restrict__ zout)
{
  const int t = threadIdx.x, w = t >> 6, lane = t & 63;
  const int n = blockIdx.x * 4 + w;
  const float lg = logits[(long long)n * 64 + lane];
  float z = lg * lg;
#pragma unroll
  for (int off = 32; off; off >>= 1) z += __shfl_xor(z, off);
  __shared__ float zs[4];
  if (lane == 0) zs[w] = z;
  __syncthreads();
  if (t == 0) atomicAdd(zout, (zs[0]+zs[1]+zs[2]+zs[3]) * (0.0001f / 262144.0f));

  float cur = lg;
  float tl[4]; int ti[4];
#pragma unroll
  for (int k = 0; k < 4; ++k){
    float s = cur; int si = lane;
#pragma unroll
    for (int off = 32; off; off >>= 1){
      float so = __shfl_xor(s, off); int io = __shfl_xor(si, off);
      if (so > s || (so == s && io < si)){ s = so; si = io; }
    }
    tl[k] = s; ti[k] = si;
    if (lane == si) cur = -3.0e38f;
  }
  if (lane == 0){
    const float m0 = tl[0];
    const float e0 = __expf(tl[0]-m0), e1 = __expf(tl[1]-m0),
                e2 = __expf(tl[2]-m0), e3 = __expf(tl[3]-m0);
    const float inv = 1.0f / (e0 + e1 + e2 + e3);
    topk[n*4+0] = ti[0]; topk[n*4+1] = ti[1]; topk[n*4+2] = ti[2]; topk[n*4+3] = ti[3];
    gating[n*4+0] = e0*inv; gating[n*4+1] = e1*inv; gating[n*4+2] = e2*inv; gating[n*4+3] = e3*inv;
  }
}

// ---------------- deterministic per-expert rank scan ----------------
__global__ void scan_route(const int* __restrict__ topk, int* __restrict__ gm,
                           int* __restrict__ rev, int* __restrict__ counts)
{
  const int e = blockIdx.x;
  const int t = threadIdx.x, w = t >> 6, lane = t & 63;
  __shared__ int wtot[4];
  int running = 0;
  for (int c = 0; c < 16384; c += 256){
    const int j = c + t;
    const bool p = (topk[j] == e);
    const unsigned long long m = __ballot(p);
    const int prefix = __popcll(m & ((1ull << lane) - 1ull));
    if (lane == 0) wtot[w] = __popcll(m);
    __syncthreads();
    int woff = 0;
#pragma unroll
    for (int i = 0; i < 4; ++i){ if (i < w) woff += wtot[i]; }
    const int btot = wtot[0] + wtot[1] + wtot[2] + wtot[3];
    if (p){
      const int rank = running + woff + prefix;
      gm[j] = (rank < MAXLD) ? (e * MAXLD + rank) : NSLOT;
      if (rank < MAXLD) rev[e * MAXLD + rank] = j >> 2;
    }
    running += btot;
    __syncthreads();
  }
  if (t == 0) counts[e] = running;
}

// ---------------- gather down-projected tokens into expert slots ----------------
__global__ void gather_pad(const unsigned short* __restrict__ down, const int* __restrict__ rev,
                           const int* __restrict__ counts, unsigned short* __restrict__ pad)
{
  const int idx = blockIdx.x * 256 + threadIdx.x;
  const int s = idx >> 6, c8 = (idx & 63) * 8;
  const int e = s / MAXLD;
  const int r = s - e * MAXLD;
  int cnt = counts[e]; if (cnt > MAXLD) cnt = MAXLD;
  us8 v = {0,0,0,0,0,0,0,0};
  if (r < cnt){
    const int tok = rev[s];
    v = *(const us8*)(down + (long long)tok * 512 + c8);
  }
  *(us8*)(pad + (long long)s * 512 + c8) = v;
}

// ---------------- silu(G)*U elementwise ----------------
__global__ void silu_mul(const unsigned short* __restrict__ G, const unsigned short* __restrict__ U,
                         unsigned short* __restrict__ O, long long ldg, long long ldu, long long ldo,
                         long long cols8, long long total)
{
  const long long idx = (long long)blockIdx.x * 256 + threadIdx.x;
  if (idx >= total) return;
  const long long rr = idx / cols8;
  const long long cc = (idx - rr * cols8) * 8;
  us8 g = *(const us8*)(G + rr * ldg + cc);
  us8 u = *(const us8*)(U + rr * ldu + cc);
  us8 o;
#pragma unroll
  for (int j = 0; j < 8; ++j){
    const float gf = bf2f(g[j]);
    const float s = gf / (1.0f + __expf(-gf));
    o[j] = f2bf(s * bf2f(u[j]));
  }
  *(us8*)(O + rr * ldo + cc) = o;
}

// ---------------- gating-weighted combine ----------------
__global__ void combine_moe(const unsigned short* __restrict__ po, const int* __restrict__ gm,
                            const float* __restrict__ gating, unsigned short* __restrict__ routed)
{
  const int idx = blockIdx.x * 256 + threadIdx.x;
  const int n = idx >> 6, c8 = (idx & 63) * 8;
  float acc[8] = {0,0,0,0,0,0,0,0};
#pragma unroll
  for (int k = 0; k < 4; ++k){
    const int slot = gm[n*4 + k];
    if (slot < NSLOT){
      const float gw = gating[n*4 + k];
      us8 v = *(const us8*)(po + (long long)slot * 512 + c8);
#pragma unroll
      for (int j = 0; j < 8; ++j) acc[j] += gw * bf2f(v[j]);
    }
  }
  us8 o;
#pragma unroll
  for (int j = 0; j < 8; ++j) o[j] = f2bf(acc[j]);
  *(us8*)(routed + (long long)n * 512 + c8) = o;
}

// =====================================================================
extern "C" void kernel_launch(void* const* d_in, const int* in_sizes, int n_in,
                              void* d_out, int out_size, void* d_ws, size_t ws_size,
                              hipStream_t stream)
{
  const float* x      = (const float*)d_in[0];
  const float* rw     = (const float*)d_in[1];
  const float* gate_w = (const float*)d_in[2];
  const float* up_w   = (const float*)d_in[3];
  const float* down_w = (const float*)d_in[4];
  const float* w_down = (const float*)d_in[5];
  const float* w_up   = (const float*)d_in[6];
  const float* w12    = (const float*)d_in[7];
  const float* w3     = (const float*)d_in[8];
  float* out = (float*)d_out;

  char* ws = (char*)d_ws;
  unsigned short* HBF   = (unsigned short*)(ws + 0ull);
  unsigned short* RWBF  = (unsigned short*)(ws + 16777216ull);
  unsigned short* GATEB = (unsigned short*)(ws + 17039360ull);
  unsigned short* UPB   = (unsigned short*)(ws + 50593792ull);
  unsigned short* DWB   = (unsigned short*)(ws + 84148224ull);
  unsigned short* WDB   = (unsigned short*)(ws + 117702656ull);
  unsigned short* WUB   = (unsigned short*)(ws + 119799808ull);
  unsigned short* W12T  = (unsigned short*)(ws + 121896960ull);
  unsigned short* W3T   = (unsigned short*)(ws + 323223552ull);
  float*          LOGIT = (float*)(ws + 423886848ull);
  int*            TOPKI = (int*)(ws + 424935424ull);
  float*          GATE4 = (float*)(ws + 425000960ull);
  int*            GM    = (int*)(ws + 425066496ull);
  int*            CNT   = (int*)(ws + 425132032ull);
  int*            REV   = (int*)(ws + 425132288ull);
  unsigned short* GU    = (unsigned short*)(ws + 425210112ull);
  unsigned short* ACTS  = (unsigned short*)(ws + 559427840ull);
  float*          SHRD  = (float*)(ws + 626536704ull);
  unsigned short* DNB   = (unsigned short*)(ws + 660091136ull);
  unsigned short* PAD   = (unsigned short*)(ws + 664285440ull);
  unsigned short* PO    = (unsigned short*)(ws + 684208384ull);
  unsigned short* RTD   = (unsigned short*)(ws + 704131328ull);

  hipMemsetAsync((char*)d_out + 8388608ull * 4, 0, 4, stream);

  // bf16 conversions
  cvt_bf16<<<8192,  256, 0, stream>>>(x,      HBF,   2097152);
  cvt_bf16<<<128,   256, 0, stream>>>(rw,     RWBF,  32768);
  cvt_bf16<<<16384, 256, 0, stream>>>(gate_w, GATEB, 4194304);
  cvt_bf16<<<16384, 256, 0, stream>>>(up_w,   UPB,   4194304);
  cvt_bf16<<<16384, 256, 0, stream>>>(down_w, DWB,   4194304);
  cvt_bf16<<<1024,  256, 0, stream>>>(w_down, WDB,   262144);
  cvt_bf16<<<1024,  256, 0, stream>>>(w_up,   WUB,   262144);
  transpose_cvt<<<dim3(96,16,64), 256, 0, stream>>>(w12, W12T, 512, 3072);
  transpose_cvt<<<dim3(16,48,64), 256, 0, stream>>>(w3,  W3T,  1536, 512);

  // router
  gemm_bt<1><<<dim3(1,32,1), 256, 0, stream>>>(HBF, RWBF, LOGIT, nullptr,
                                               4096, 64, 2048, 0, 0, 0);
  router_topk<<<1024, 256, 0, stream>>>(LOGIT, TOPKI, GATE4, out + 8388608);
  scan_route<<<64, 256, 0, stream>>>(TOPKI, GM, REV, CNT);

  // shared expert (8-phase pipelined GEMMs)
  gemm8p<256,0><<<dim3(32,16), 512, 0, stream>>>(HBF, GATEB, GU, nullptr, 4096, 8192, 2048);
  gemm8p<256,0><<<dim3(32,16), 512, 0, stream>>>(HBF, UPB, GU + 33554432ull, nullptr, 4096, 8192, 2048);
  silu_mul<<<16384, 256, 0, stream>>>(GU, GU + 33554432ull, ACTS, 8192, 8192, 8192,
                                      1024, 4194304);
  gemm8p<128,1><<<dim3(8,32), 512, 0, stream>>>(ACTS, DWB, SHRD, nullptr, 4096, 2048, 8192);

  // MoE path
  gemm_bt<0><<<dim3(4,32,1), 256, 0, stream>>>(HBF, WDB, DNB, nullptr,
                                               4096, 512, 2048, 0, 0, 0);
  gather_pad<<<4864, 256, 0, stream>>>(DNB, REV, CNT, PAD);
  gemm_bt<0><<<dim3(24,3,64), 256, 0, stream>>>(PAD, W12T, GU, nullptr,
                                                304, 3072, 512, 155648, 1572864, 933888);
  silu_mul<<<14592, 256, 0, stream>>>(GU, GU + 1536, ACTS, 3072, 3072, 1536,
                                      192, 3735552);
  gemm_bt<0><<<dim3(4,3,64), 256, 0, stream>>>(ACTS, W3T, PO, nullptr,
                                               304, 512, 1536, 466944, 786432, 155648);
  combine_moe<<<1024, 256, 0, stream>>>(PO, GM, GATE4, RTD);

  // final: out = (shared + routed @ w_up^T) * 0.5
  gemm8p<128,2><<<dim3(8,32), 512, 0, stream>>>(RTD, WUB, out, SHRD, 4096, 2048, 512);
}

// Round 4
// 1151.877 us; speedup vs baseline: 1.1682x; 1.0512x over previous
//
#include <hip/hip_runtime.h>

#define DEV __device__ __forceinline__

typedef __attribute__((ext_vector_type(4))) float f4;
typedef __attribute__((ext_vector_type(8))) __bf16 bfrag;
typedef __attribute__((ext_vector_type(4))) unsigned short us4;
typedef __attribute__((ext_vector_type(8))) unsigned short us8;

// problem constants
#define NTOK   4096
#define DMODEL 2048
#define NEXP   64
#define MAXLD  304
#define NSLOT  19456   // 64*304

DEV unsigned short f2bf(float f){
  union { float f; unsigned int i; } u; u.f = f;
  unsigned int r = u.i + 0x7fffu + ((u.i >> 16) & 1u);
  return (unsigned short)(r >> 16);
}
DEV float bf2f(unsigned short b){
  union { unsigned int i; float f; } u; u.i = ((unsigned int)b) << 16;
  return u.f;
}

DEV void gl_lds16(const unsigned short* g, unsigned short* l){
  __builtin_amdgcn_global_load_lds(
      (const __attribute__((address_space(1))) void*)g,
      (__attribute__((address_space(3))) void*)l, 16, 0, 0);
}

// ============== deep-prefetch GEMM: C = A @ B^T ======================
// A: M x K bf16, B: N x K bf16 (row-major, K-contig). BN = 256, BK = 32.
// 512 threads = 8 waves (2M x 4N), wave tile (BM/2) x 64.
// 4 LDS buffers; prefetch 3 K-tiles ahead; per tile exactly ONE counted
// vmcnt wait + ONE barrier around a 32(/16)-MFMA cluster.
// Ledger (LPT loads/tile): prologue stages t=0,1,2 (3*LPT in flight),
// wait(2*LPT) certifies t=0. Iter t: read buf[t&3]; stage t+3 into
// buf[(t+3)&3]=buf[(t-1)&3] (WAR-safe: last read at t-1, barrier between);
// MFMA; wait(2*LPT) leaves t+2,t+3 in flight, certifies t+1; barrier.
// Tail: rem = nt-2-t: rem>=2 -> 2*LPT, rem==1 -> LPT, rem==0 -> 0, else none.
// LDS swizzle: k-chunk kg ^ ((row>>1)&3), involution pre-applied on the
// global source so global_load_lds dest stays linear (measured: 0 conflicts).
// EPI: 0 = bf16 out, 1 = f32 out, 2 = f32 out = (acc + addin)*0.5
template<int BM, int EPI>
__global__ __launch_bounds__(512, 2) void gemmdp(
    const unsigned short* __restrict__ A, const unsigned short* __restrict__ B,
    void* __restrict__ Cp, const float* __restrict__ addin, int M, int N, int K)
{
  constexpr int FM  = BM / 32;     // A frags per wave (8 or 4)
  constexpr int ALD = BM / 128;    // A gl_lds16 per thread per tile (2 or 1)
  __shared__ unsigned short As[4][BM * 32];
  __shared__ unsigned short Bs[4][256 * 32];

  // bijective XCD swizzle (all call-site grids are multiples of 8)
  const int nwg = gridDim.x * gridDim.y;
  int bid = blockIdx.y * gridDim.x + blockIdx.x;
  bid = (bid & 7) * (nwg >> 3) + (bid >> 3);
  const int bx = bid % gridDim.x, by = bid / gridDim.x;
  const int bm = by * BM, bn = bx * 256;

  const int t = threadIdx.x, lane = t & 63, wave = t >> 6;
  const int wm = (wave >> 2) * (BM / 2), wn = (wave & 3) * 64;
  const int fr = lane & 15, kg = lane >> 4;

  // staging: chunk c (16B) = row c>>2, k-slot c&3; source k-chunk = (c&3)^((c>>3)&3)
  const int sw = ((t >> 3) & 3) ^ (t & 3);
  const unsigned short* a_src0 = A + (long long)(bm + (t >> 2)) * K + sw * 8;
  const unsigned short* a_src1 = A + (long long)(bm + (t >> 2) + 128) * K + sw * 8;
  const unsigned short* b_src0 = B + (long long)(bn + (t >> 2)) * K + sw * 8;
  const unsigned short* b_src1 = B + (long long)(bn + (t >> 2) + 128) * K + sw * 8;
  const int wch = wave * 64;   // wave-uniform LDS chunk base (HW adds lane*16B)

#define STG(bv, tt_) do { const long long ko_ = (long long)(tt_) * 32;            \
    gl_lds16(a_src0 + ko_, &As[bv][wch * 8]);                                     \
    if (ALD == 2) gl_lds16(a_src1 + ko_, &As[bv][(512 + wch) * 8]);               \
    gl_lds16(b_src0 + ko_, &Bs[bv][wch * 8]);                                     \
    gl_lds16(b_src1 + ko_, &Bs[bv][(512 + wch) * 8]); } while (0)

  f4 acc[FM][4];
#pragma unroll
  for (int m = 0; m < FM; ++m)
#pragma unroll
    for (int n = 0; n < 4; ++n) acc[m][n] = f4{0.f, 0.f, 0.f, 0.f};

  const int nt = K >> 5;   // all call sites: nt >= 16

  // prologue: stage tiles 0,1,2
  STG(0, 0); STG(1, 1); STG(2, 2);
  if constexpr (ALD == 2) asm volatile("s_waitcnt vmcnt(8)" ::: "memory");
  else                    asm volatile("s_waitcnt vmcnt(6)" ::: "memory");
  __builtin_amdgcn_s_barrier();
  __builtin_amdgcn_sched_barrier(0);

  for (int tt = 0; tt < nt; ++tt){
    const unsigned short* Ab = As[tt & 3];
    const unsigned short* Bb = Bs[tt & 3];
    bfrag bfv[4], af[FM];
#pragma unroll
    for (int n = 0; n < 4; ++n){
      const int r = wn + n * 16 + fr;
      bfv[n] = *(const bfrag*)&Bb[r * 32 + ((kg ^ ((r >> 1) & 3)) << 3)];
    }
#pragma unroll
    for (int m = 0; m < FM; ++m){
      const int r = wm + m * 16 + fr;
      af[m] = *(const bfrag*)&Ab[r * 32 + ((kg ^ ((r >> 1) & 3)) << 3)];
    }
    if (tt + 3 < nt) STG((tt + 3) & 3, tt + 3);
    asm volatile("s_waitcnt lgkmcnt(0)" ::: "memory");
    __builtin_amdgcn_sched_barrier(0);
    __builtin_amdgcn_s_setprio(1);
#pragma unroll
    for (int m = 0; m < FM; ++m)
#pragma unroll
      for (int n = 0; n < 4; ++n)
        acc[m][n] = __builtin_amdgcn_mfma_f32_16x16x32_bf16(af[m], bfv[n], acc[m][n], 0, 0, 0);
    __builtin_amdgcn_s_setprio(0);
    __builtin_amdgcn_sched_barrier(0);

    const int rem = nt - 2 - tt;
    if constexpr (ALD == 2){
      if (rem >= 2)      asm volatile("s_waitcnt vmcnt(8)" ::: "memory");
      else if (rem == 1) asm volatile("s_waitcnt vmcnt(4)" ::: "memory");
      else if (rem == 0) asm volatile("s_waitcnt vmcnt(0)" ::: "memory");
    } else {
      if (rem >= 2)      asm volatile("s_waitcnt vmcnt(6)" ::: "memory");
      else if (rem == 1) asm volatile("s_waitcnt vmcnt(3)" ::: "memory");
      else if (rem == 0) asm volatile("s_waitcnt vmcnt(0)" ::: "memory");
    }
    if (tt + 1 < nt){
      __builtin_amdgcn_s_barrier();
      __builtin_amdgcn_sched_barrier(0);
    }
  }

  // epilogue: C/D layout col=lane&15, row=(lane>>4)*4+reg
#pragma unroll
  for (int m = 0; m < FM; ++m){
    const int row0 = bm + wm + m * 16 + kg * 4;
#pragma unroll
    for (int n = 0; n < 4; ++n){
      const int col = bn + wn + n * 16 + fr;
      f4 v = acc[m][n];
#pragma unroll
      for (int r = 0; r < 4; ++r){
        const long long off = (long long)(row0 + r) * N + col;
        if (EPI == 0)      ((unsigned short*)Cp)[off] = f2bf(v[r]);
        else if (EPI == 1) ((float*)Cp)[off] = v[r];
        else               ((float*)Cp)[off] = (v[r] + addin[off]) * 0.5f;
      }
    }
  }
#undef STG
}

// ---------------- generic 128x128 C = A @ B^T GEMM (bounds-checked) --------
// EPI: 0 = bf16 out, 1 = f32 out, 2 = f32 out = (acc + addin)*0.5
template<int EPI>
__global__ __launch_bounds__(256) void gemm_bt(
    const unsigned short* __restrict__ A, const unsigned short* __restrict__ B,
    void* __restrict__ Cp, const float* __restrict__ addin,
    int M, int N, int K, long long sA, long long sB, long long sC)
{
  __shared__ unsigned short As[128*32];
  __shared__ unsigned short Bs[128*32];
  A += (long long)blockIdx.z * sA;
  B += (long long)blockIdx.z * sB;
  const long long cbase = (long long)blockIdx.z * sC;
  const int bm = blockIdx.y * 128, bn = blockIdx.x * 128;
  const int t = threadIdx.x, wave = t >> 6, lane = t & 63;
  const int wm = (wave >> 1) * 64, wn = (wave & 1) * 64;
  const int fr = lane & 15, kg = lane >> 4;

  f4 acc[4][4];
#pragma unroll
  for (int m = 0; m < 4; ++m)
#pragma unroll
    for (int n = 0; n < 4; ++n)
      acc[m][n] = f4{0.f, 0.f, 0.f, 0.f};

  const int i0 = t, i1 = 256 + t;
  int ar0 = bm + (i0 >> 2); if (ar0 > M - 1) ar0 = M - 1;
  int ar1 = bm + (i1 >> 2); if (ar1 > M - 1) ar1 = M - 1;
  int br0 = bn + (i0 >> 2); if (br0 > N - 1) br0 = N - 1;
  int br1 = bn + (i1 >> 2); if (br1 > N - 1) br1 = N - 1;
  const unsigned short* ap0 = A + (long long)ar0 * K + (i0 & 3) * 8;
  const unsigned short* ap1 = A + (long long)ar1 * K + (i1 & 3) * 8;
  const unsigned short* bp0 = B + (long long)br0 * K + (i0 & 3) * 8;
  const unsigned short* bp1 = B + (long long)br1 * K + (i1 & 3) * 8;
  unsigned short* da0 = As + wave * 512;
  unsigned short* da1 = As + 2048 + wave * 512;
  unsigned short* db0 = Bs + wave * 512;
  unsigned short* db1 = Bs + 2048 + wave * 512;

  for (int k0 = 0; k0 < K; k0 += 32){
    gl_lds16(ap0, da0);
    gl_lds16(ap1, da1);
    gl_lds16(bp0, db0);
    gl_lds16(bp1, db1);
    ap0 += 32; ap1 += 32; bp0 += 32; bp1 += 32;
    __syncthreads();
    bfrag af[4], bfv[4];
#pragma unroll
    for (int m = 0; m < 4; ++m) af[m] = *(const bfrag*)&As[(wm + m*16 + fr)*32 + kg*8];
#pragma unroll
    for (int n = 0; n < 4; ++n) bfv[n] = *(const bfrag*)&Bs[(wn + n*16 + fr)*32 + kg*8];
#pragma unroll
    for (int m = 0; m < 4; ++m)
#pragma unroll
      for (int n = 0; n < 4; ++n)
        acc[m][n] = __builtin_amdgcn_mfma_f32_16x16x32_bf16(af[m], bfv[n], acc[m][n], 0, 0, 0);
    __syncthreads();
  }

#pragma unroll
  for (int m = 0; m < 4; ++m){
    const int row0 = bm + wm + m*16 + kg*4;
#pragma unroll
    for (int n = 0; n < 4; ++n){
      const int col = bn + wn + n*16 + fr;
      if (col < N){
        f4 v = acc[m][n];
#pragma unroll
        for (int r = 0; r < 4; ++r){
          const int row = row0 + r;
          if (row < M){
            const long long off = cbase + (long long)row * N + col;
            if (EPI == 0)      ((unsigned short*)Cp)[off] = f2bf(v[r]);
            else if (EPI == 1) ((float*)Cp)[off] = v[r];
            else               ((float*)Cp)[off] = (v[r] + addin[off]) * 0.5f;
          }
        }
      }
    }
  }
}

// ---------------- f32 -> bf16 convert (vectorized) ----------------
__global__ void cvt_bf16(const float* __restrict__ in, unsigned short* __restrict__ out,
                         long long n4)
{
  long long i = (long long)blockIdx.x * 256 + threadIdx.x;
  if (i >= n4) return;
  float4 v = ((const float4*)in)[i];
  us4 o; o[0] = f2bf(v.x); o[1] = f2bf(v.y); o[2] = f2bf(v.z); o[3] = f2bf(v.w);
  ((us4*)out)[i] = o;
}

// ---------------- [z][R][C] f32 -> [z][C][R] bf16 ----------------
__global__ __launch_bounds__(256) void transpose_cvt(const float* __restrict__ in,
    unsigned short* __restrict__ out, int R, int C)
{
  __shared__ float tile[32][33];
  const long long z = blockIdx.z;
  const float* ip = in + z * (long long)R * C;
  unsigned short* op = out + z * (long long)R * C;
  const int r0 = blockIdx.y * 32, c0 = blockIdx.x * 32;
  const int t = threadIdx.x;
  const int lr = t >> 3, lc = (t & 7) * 4;
  float4 v = *(const float4*)(ip + (long long)(r0 + lr) * C + c0 + lc);
  tile[lr][lc+0] = v.x; tile[lr][lc+1] = v.y; tile[lr][lc+2] = v.z; tile[lr][lc+3] = v.w;
  __syncthreads();
  const int oc = t >> 3, orr = (t & 7) * 4;
  us4 o;
  o[0] = f2bf(tile[orr+0][oc]); o[1] = f2bf(tile[orr+1][oc]);
  o[2] = f2bf(tile[orr+2][oc]); o[3] = f2bf(tile[orr+3][oc]);
  *(us4*)(op + (long long)(c0 + oc) * R + r0 + orr) = o;
}

// ---------------- router: top-4, softmax gating, z-loss ----------------
__global__ void router_topk(const float* __restrict__ logits, int* __restrict__ topk,
                            float* __restrict__ gating, float* __restrict__ zout)
{
  const int t = threadIdx.x, w = t >> 6, lane = t & 63;
  const int n = blockIdx.x * 4 + w;
  const float lg = logits[(long long)n * 64 + lane];
  float z = lg * lg;
#pragma unroll
  for (int off = 32; off; off >>= 1) z += __shfl_xor(z, off);
  __shared__ float zs[4];
  if (lane == 0) zs[w] = z;
  __syncthreads();
  if (t == 0) atomicAdd(zout, (zs[0]+zs[1]+zs[2]+zs[3]) * (0.0001f / 262144.0f));

  float cur = lg;
  float tl[4]; int ti[4];
#pragma unroll
  for (int k = 0; k < 4; ++k){
    float s = cur; int si = lane;
#pragma unroll
    for (int off = 32; off; off >>= 1){
      float so = __shfl_xor(s, off); int io = __shfl_xor(si, off);
      if (so > s || (so == s && io < si)){ s = so; si = io; }
    }
    tl[k] = s; ti[k] = si;
    if (lane == si) cur = -3.0e38f;
  }
  if (lane == 0){
    const float m0 = tl[0];
    const float e0 = __expf(tl[0]-m0), e1 = __expf(tl[1]-m0),
                e2 = __expf(tl[2]-m0), e3 = __expf(tl[3]-m0);
    const float inv = 1.0f / (e0 + e1 + e2 + e3);
    topk[n*4+0] = ti[0]; topk[n*4+1] = ti[1]; topk[n*4+2] = ti[2]; topk[n*4+3] = ti[3];
    gating[n*4+0] = e0*inv; gating[n*4+1] = e1*inv; gating[n*4+2] = e2*inv; gating[n*4+3] = e3*inv;
  }
}

// ---------------- deterministic per-expert rank scan ----------------
__global__ void scan_route(const int* __restrict__ topk, int* __restrict__ gm,
                           int* __restrict__ rev, int* __restrict__ counts)
{
  const int e = blockIdx.x;
  const int t = threadIdx.x, w = t >> 6, lane = t & 63;
  __shared__ int wtot[4];
  int running = 0;
  for (int c = 0; c < 16384; c += 256){
    const int j = c + t;
    const bool p = (topk[j] == e);
    const unsigned long long m = __ballot(p);
    const int prefix = __popcll(m & ((1ull << lane) - 1ull));
    if (lane == 0) wtot[w] = __popcll(m);
    __syncthreads();
    int woff = 0;
#pragma unroll
    for (int i = 0; i < 4; ++i){ if (i < w) woff += wtot[i]; }
    const int btot = wtot[0] + wtot[1] + wtot[2] + wtot[3];
    if (p){
      const int rank = running + woff + prefix;
      gm[j] = (rank < MAXLD) ? (e * MAXLD + rank) : NSLOT;
      if (rank < MAXLD) rev[e * MAXLD + rank] = j >> 2;
    }
    running += btot;
    __syncthreads();
  }
  if (t == 0) counts[e] = running;
}

// ---------------- gather down-projected tokens into expert slots ----------------
__global__ void gather_pad(const unsigned short* __restrict__ down, const int* __restrict__ rev,
                           const int* __restrict__ counts, unsigned short* __restrict__ pad)
{
  const int idx = blockIdx.x * 256 + threadIdx.x;
  const int s = idx >> 6, c8 = (idx & 63) * 8;
  const int e = s / MAXLD;
  const int r = s - e * MAXLD;
  int cnt = counts[e]; if (cnt > MAXLD) cnt = MAXLD;
  us8 v = {0,0,0,0,0,0,0,0};
  if (r < cnt){
    const int tok = rev[s];
    v = *(const us8*)(down + (long long)tok * 512 + c8);
  }
  *(us8*)(pad + (long long)s * 512 + c8) = v;
}

// ---------------- silu(G)*U elementwise ----------------
__global__ void silu_mul(const unsigned short* __restrict__ G, const unsigned short* __restrict__ U,
                         unsigned short* __restrict__ O, long long ldg, long long ldu, long long ldo,
                         long long cols8, long long total)
{
  const long long idx = (long long)blockIdx.x * 256 + threadIdx.x;
  if (idx >= total) return;
  const long long rr = idx / cols8;
  const long long cc = (idx - rr * cols8) * 8;
  us8 g = *(const us8*)(G + rr * ldg + cc);
  us8 u = *(const us8*)(U + rr * ldu + cc);
  us8 o;
#pragma unroll
  for (int j = 0; j < 8; ++j){
    const float gf = bf2f(g[j]);
    const float s = gf / (1.0f + __expf(-gf));
    o[j] = f2bf(s * bf2f(u[j]));
  }
  *(us8*)(O + rr * ldo + cc) = o;
}

// ---------------- gating-weighted combine ----------------
__global__ void combine_moe(const unsigned short* __restrict__ po, const int* __restrict__ gm,
                            const float* __restrict__ gating, unsigned short* __restrict__ routed)
{
  const int idx = blockIdx.x * 256 + threadIdx.x;
  const int n = idx >> 6, c8 = (idx & 63) * 8;
  float acc[8] = {0,0,0,0,0,0,0,0};
#pragma unroll
  for (int k = 0; k < 4; ++k){
    const int slot = gm[n*4 + k];
    if (slot < NSLOT){
      const float gw = gating[n*4 + k];
      us8 v = *(const us8*)(po + (long long)slot * 512 + c8);
#pragma unroll
      for (int j = 0; j < 8; ++j) acc[j] += gw * bf2f(v[j]);
    }
  }
  us8 o;
#pragma unroll
  for (int j = 0; j < 8; ++j) o[j] = f2bf(acc[j]);
  *(us8*)(routed + (long long)n * 512 + c8) = o;
}

// =====================================================================
extern "C" void kernel_launch(void* const* d_in, const int* in_sizes, int n_in,
                              void* d_out, int out_size, void* d_ws, size_t ws_size,
                              hipStream_t stream)
{
  const float* x      = (const float*)d_in[0];
  const float* rw     = (const float*)d_in[1];
  const float* gate_w = (const float*)d_in[2];
  const float* up_w   = (const float*)d_in[3];
  const float* down_w = (const float*)d_in[4];
  const float* w_down = (const float*)d_in[5];
  const float* w_up   = (const float*)d_in[6];
  const float* w12    = (const float*)d_in[7];
  const float* w3     = (const float*)d_in[8];
  float* out = (float*)d_out;

  char* ws = (char*)d_ws;
  unsigned short* HBF   = (unsigned short*)(ws + 0ull);
  unsigned short* RWBF  = (unsigned short*)(ws + 16777216ull);
  unsigned short* GATEB = (unsigned short*)(ws + 17039360ull);
  unsigned short* UPB   = (unsigned short*)(ws + 50593792ull);
  unsigned short* DWB   = (unsigned short*)(ws + 84148224ull);
  unsigned short* WDB   = (unsigned short*)(ws + 117702656ull);
  unsigned short* WUB   = (unsigned short*)(ws + 119799808ull);
  unsigned short* W12T  = (unsigned short*)(ws + 121896960ull);
  unsigned short* W3T   = (unsigned short*)(ws + 323223552ull);
  float*          LOGIT = (float*)(ws + 423886848ull);
  int*            TOPKI = (int*)(ws + 424935424ull);
  float*          GATE4 = (float*)(ws + 425000960ull);
  int*            GM    = (int*)(ws + 425066496ull);
  int*            CNT   = (int*)(ws + 425132032ull);
  int*            REV   = (int*)(ws + 425132288ull);
  unsigned short* GU    = (unsigned short*)(ws + 425210112ull);
  unsigned short* ACTS  = (unsigned short*)(ws + 559427840ull);
  float*          SHRD  = (float*)(ws + 626536704ull);
  unsigned short* DNB   = (unsigned short*)(ws + 660091136ull);
  unsigned short* PAD   = (unsigned short*)(ws + 664285440ull);
  unsigned short* PO    = (unsigned short*)(ws + 684208384ull);
  unsigned short* RTD   = (unsigned short*)(ws + 704131328ull);

  hipMemsetAsync((char*)d_out + 8388608ull * 4, 0, 4, stream);

  // bf16 conversions
  cvt_bf16<<<8192,  256, 0, stream>>>(x,      HBF,   2097152);
  cvt_bf16<<<128,   256, 0, stream>>>(rw,     RWBF,  32768);
  cvt_bf16<<<16384, 256, 0, stream>>>(gate_w, GATEB, 4194304);
  cvt_bf16<<<16384, 256, 0, stream>>>(up_w,   UPB,   4194304);
  cvt_bf16<<<16384, 256, 0, stream>>>(down_w, DWB,   4194304);
  cvt_bf16<<<1024,  256, 0, stream>>>(w_down, WDB,   262144);
  cvt_bf16<<<1024,  256, 0, stream>>>(w_up,   WUB,   262144);
  transpose_cvt<<<dim3(96,16,64), 256, 0, stream>>>(w12, W12T, 512, 3072);
  transpose_cvt<<<dim3(16,48,64), 256, 0, stream>>>(w3,  W3T,  1536, 512);

  // router
  gemm_bt<1><<<dim3(1,32,1), 256, 0, stream>>>(HBF, RWBF, LOGIT, nullptr,
                                               4096, 64, 2048, 0, 0, 0);
  router_topk<<<1024, 256, 0, stream>>>(LOGIT, TOPKI, GATE4, out + 8388608);
  scan_route<<<64, 256, 0, stream>>>(TOPKI, GM, REV, CNT);

  // shared expert (deep-prefetch pipelined GEMMs)
  gemmdp<256,0><<<dim3(32,16), 512, 0, stream>>>(HBF, GATEB, GU, nullptr, 4096, 8192, 2048);
  gemmdp<256,0><<<dim3(32,16), 512, 0, stream>>>(HBF, UPB, GU + 33554432ull, nullptr, 4096, 8192, 2048);
  silu_mul<<<16384, 256, 0, stream>>>(GU, GU + 33554432ull, ACTS, 8192, 8192, 8192,
                                      1024, 4194304);
  gemmdp<128,1><<<dim3(8,32), 512, 0, stream>>>(ACTS, DWB, SHRD, nullptr, 4096, 2048, 8192);

  // MoE path
  gemm_bt<0><<<dim3(4,32,1), 256, 0, stream>>>(HBF, WDB, DNB, nullptr,
                                               4096, 512, 2048, 0, 0, 0);
  gather_pad<<<4864, 256, 0, stream>>>(DNB, REV, CNT, PAD);
  gemm_bt<0><<<dim3(24,3,64), 256, 0, stream>>>(PAD, W12T, GU, nullptr,
                                                304, 3072, 512, 155648, 1572864, 933888);
  silu_mul<<<14592, 256, 0, stream>>>(GU, GU + 1536, ACTS, 3072, 3072, 1536,
                                      192, 3735552);
  gemm_bt<0><<<dim3(4,3,64), 256, 0, stream>>>(ACTS, W3T, PO, nullptr,
                                               304, 512, 1536, 466944, 786432, 155648);
  combine_moe<<<1024, 256, 0, stream>>>(PO, GM, GATE4, RTD);

  // final: out = (shared + routed @ w_up^T) * 0.5
  gemmdp<128,2><<<dim3(8,32), 512, 0, stream>>>(RTD, WUB, out, SHRD, 4096, 2048, 512);
}